// Round 2
// baseline (1446.259 us; speedup 1.0000x reference)
//
#include <hip/hip_runtime.h>
#include <cstddef>

typedef __bf16 bf16;
typedef __bf16 bf16x8 __attribute__((ext_vector_type(8)));
typedef float  f32x4  __attribute__((ext_vector_type(4)));
typedef unsigned short u16;

#define MFMA16x16(a, b, c) __builtin_amdgcn_mfma_f32_16x16x32_bf16((a), (b), (c), 0, 0, 0)

namespace {
constexpr int BB   = 4;     // batch
constexpr int CIN  = 128;   // input channels
constexpr int NPT  = 4096;  // points
constexpr int KNBR = 16;    // neighbors
constexpr int HED  = 128;   // hidden (edge mlp out)
constexpr int COUT = 256;   // output channels
}

// ---------------------------------------------------------------------------
// W0: convert the three GEMM weight matrices fp32 -> bf16 (each 32768 elems)
// ---------------------------------------------------------------------------
__global__ __launch_bounds__(256) void k_wconv(const float* __restrict__ We,
                                               const float* __restrict__ Wf,
                                               const float* __restrict__ Wr,
                                               bf16* __restrict__ Web,
                                               bf16* __restrict__ Wfb,
                                               bf16* __restrict__ Wrb) {
  const int i = blockIdx.x * 256 + threadIdx.x;   // [0, 3*32768)
  const int a = i >> 15;
  const int j = i & 32767;
  const float* src = (a == 0) ? We : (a == 1) ? Wf : Wr;
  bf16*        dst = (a == 0) ? Web : (a == 1) ? Wfb : Wrb;
  dst[j] = (bf16)src[j];
}

// ---------------------------------------------------------------------------
// K0: transpose x (B,Cin,N) fp32 -> xt_hi/xt_lo (B,N,Cin) bf16 split, and
//     sq[b][n] = sum_c x^2 in fp32 (matches reference's fp32 sq).
// ---------------------------------------------------------------------------
__global__ __launch_bounds__(256) void k_prep(const float* __restrict__ x,
                                              bf16* __restrict__ xh,
                                              bf16* __restrict__ xl,
                                              float* __restrict__ sq) {
  __shared__ __attribute__((aligned(16))) bf16 th[64][136];
  __shared__ __attribute__((aligned(16))) bf16 tl[64][136];
  __shared__ float sqp[4][64];
  const int tid = threadIdx.x;
  const int b   = blockIdx.x >> 6;
  const int n0  = (blockIdx.x & 63) << 6;
  const int nl  = tid & 63;
  const int cg  = tid >> 6;
  const float* xb = x + (size_t)b * CIN * NPT;
  float acc = 0.f;
  #pragma unroll
  for (int rep = 0; rep < 32; ++rep) {
    const int c = rep * 4 + cg;
    const float v = xb[(size_t)c * NPT + n0 + nl];
    const bf16 h = (bf16)v;
    const bf16 l = (bf16)(v - (float)h);
    acc += v * v;
    th[nl][c] = h;
    tl[nl][c] = l;
  }
  sqp[cg][nl] = acc;
  __syncthreads();
  bf16* xho = xh + ((size_t)b * NPT + n0) * CIN;
  bf16* xlo = xl + ((size_t)b * NPT + n0) * CIN;
  #pragma unroll
  for (int rep = 0; rep < 32; ++rep) {
    const int e = rep * 256 + tid;
    const int r = e >> 7;
    const int c = e & 127;
    xho[(size_t)r * CIN + c] = th[r][c];
    xlo[(size_t)r * CIN + c] = tl[r][c];
  }
  if (tid < 64) {
    sq[b * NPT + n0 + tid] = sqp[0][tid] + sqp[1][tid] + sqp[2][tid] + sqp[3][tid];
  }
}

// ---------------------------------------------------------------------------
// K1: KNN. Block = 64 rows (4 waves x 16 rows). Gram tile via split-bf16 MFMA
// (hh + hl + lh -> fp32-equivalent dot, d2 err ~1e-4 << rank-16/17 gap ~0.7).
// d2 = (sqn+sqm)-2*dot matching reference association. Top-16 insertion lists
// in registers; strict <, increasing-m scan -> lax.top_k tie semantics.
// ---------------------------------------------------------------------------
__global__ __launch_bounds__(256) void k_knn(const bf16* __restrict__ xh,
                                             const bf16* __restrict__ xl,
                                             const float* __restrict__ sq,
                                             int* __restrict__ knn_idx) {
  __shared__ __attribute__((aligned(16))) float G[4][16][65];
  const int tid  = threadIdx.x;
  const int w    = tid >> 6;
  const int lane = tid & 63;
  const int col  = lane & 15;
  const int quad = lane >> 4;
  const int b    = blockIdx.x >> 6;
  const int n0   = (blockIdx.x & 63) << 6;
  const bf16*  xhb = xh + (size_t)b * NPT * CIN;
  const bf16*  xlb = xl + (size_t)b * NPT * CIN;
  const float* sqb = sq + b * NPT;

  bf16x8 ah[4], al[4];
  {
    const bf16* ar = xhb + (size_t)(n0 + w * 16 + col) * CIN + quad * 8;
    const bf16* al_ = xlb + (size_t)(n0 + w * 16 + col) * CIN + quad * 8;
    #pragma unroll
    for (int ks = 0; ks < 4; ++ks) {
      ah[ks] = *(const bf16x8*)(ar + ks * 32);
      al[ks] = *(const bf16x8*)(al_ + ks * 32);
    }
  }
  const float sqn = sqb[n0 + w * 16 + col];

  float bd[16];
  int   bi[16];
  #pragma unroll
  for (int i = 0; i < 16; ++i) { bd[i] = 3.4028235e38f; bi[i] = 0; }

  for (int mt = 0; mt < 64; ++mt) {
    const int m0 = mt * 64;
    #pragma unroll
    for (int cb = 0; cb < 4; ++cb) {
      f32x4 acc = {0.f, 0.f, 0.f, 0.f};
      const bf16* brh = xhb + (size_t)(m0 + cb * 16 + col) * CIN + quad * 8;
      const bf16* brl = xlb + (size_t)(m0 + cb * 16 + col) * CIN + quad * 8;
      #pragma unroll
      for (int ks = 0; ks < 4; ++ks) {
        const bf16x8 bh = *(const bf16x8*)(brh + ks * 32);
        const bf16x8 bl = *(const bf16x8*)(brl + ks * 32);
        acc = MFMA16x16(al[ks], bh, acc);
        acc = MFMA16x16(ah[ks], bl, acc);
        acc = MFMA16x16(ah[ks], bh, acc);
      }
      #pragma unroll
      for (int r = 0; r < 4; ++r) G[w][quad * 4 + r][cb * 16 + col] = acc[r];
    }
    __syncthreads();
    if (lane < 16) {
      for (int c = 0; c < 64; ++c) {
        float d = (sqn + sqb[m0 + c]) - 2.0f * G[w][lane][c];
        if (d < bd[15]) {
          float cd = d; int cm = m0 + c; bool ins = false;
          #pragma unroll
          for (int i = 0; i < 16; ++i) {
            const bool t = ins || (cd < bd[i]);
            if (t) {
              const float td = bd[i]; const int ti = bi[i];
              bd[i] = cd; bi[i] = cm; cd = td; cm = ti; ins = true;
            }
          }
        }
      }
    }
    __syncthreads();
  }
  if (lane < 16) {
    int* op = knn_idx + (size_t)(b * NPT + n0 + w * 16 + lane) * KNBR;
    #pragma unroll
    for (int i = 0; i < 16; ++i) op[i] = bi[i];
  }
}

// ---------------------------------------------------------------------------
// K2: edge MLP + attention + aggregate. One wave per point, 4 points per wave.
// Gathers hi+lo, reconstructs fp32, builds edge=[neigh-center, center] in LDS
// as bf16 (single rounding). h kept in fp32 registers; softmax + aggregate via
// shfl_xor reductions.
// ---------------------------------------------------------------------------
__global__ __launch_bounds__(256) void k_edge(const bf16* __restrict__ xh,
                                              const bf16* __restrict__ xl,
                                              const int* __restrict__ knn_idx,
                                              const bf16* __restrict__ We,
                                              const float* __restrict__ g1, const float* __restrict__ b1,
                                              const float* __restrict__ m1, const float* __restrict__ v1,
                                              const float* __restrict__ watt,
                                              bf16* __restrict__ agg) {
  __shared__ __attribute__((aligned(16))) bf16 Ew[4][16][264];
  __shared__ float s1[HED], t1[HED], wat[HED];
  const int tid  = threadIdx.x;
  const int w    = tid >> 6;
  const int lane = tid & 63;
  const int col  = lane & 15;
  const int quad = lane >> 4;
  if (tid < HED) {
    const float ss = g1[tid] / sqrtf(v1[tid] + 1e-5f);
    s1[tid] = ss;
    t1[tid] = b1[tid] - m1[tid] * ss;
    wat[tid] = watt[tid];
  }
  __syncthreads();
  const int gw = blockIdx.x * 4 + w;
  for (int it = 0; it < 4; ++it) {
    const int p = gw * 4 + it;
    const int b = p >> 12;
    const int n = p & 4095;
    const bf16* xhb = xh + (size_t)b * NPT * CIN;
    const bf16* xlb = xl + (size_t)b * NPT * CIN;
    const int my = knn_idx[(size_t)p * KNBR + col];
    const int m  = __shfl(my, lane >> 2);
    const int sub = lane & 3;
    const int kn  = lane >> 2;
    const bf16* nh = xhb + (size_t)m * CIN + sub * 32;
    const bf16* nl_ = xlb + (size_t)m * CIN + sub * 32;
    const bf16* ch = xhb + (size_t)n * CIN + sub * 32;
    const bf16* cl = xlb + (size_t)n * CIN + sub * 32;
    #pragma unroll
    for (int j = 0; j < 4; ++j) {
      const bf16x8 nhv = *(const bf16x8*)(nh + j * 8);
      const bf16x8 nlv = *(const bf16x8*)(nl_ + j * 8);
      const bf16x8 chv = *(const bf16x8*)(ch + j * 8);
      const bf16x8 clv = *(const bf16x8*)(cl + j * 8);
      bf16x8 dv, cv;
      #pragma unroll
      for (int e = 0; e < 8; ++e) {
        const float nf = (float)nhv[e] + (float)nlv[e];
        const float cf = (float)chv[e] + (float)clv[e];
        dv[e] = (bf16)(nf - cf);
        cv[e] = (bf16)cf;
      }
      *(bf16x8*)&Ew[w][kn][sub * 32 + j * 8]       = dv;
      *(bf16x8*)&Ew[w][kn][128 + sub * 32 + j * 8] = cv;
    }
    __syncthreads();
    const f32x4 zero4 = {0.f, 0.f, 0.f, 0.f};
    f32x4 acc[8];
    #pragma unroll
    for (int hb = 0; hb < 8; ++hb) acc[hb] = zero4;
    #pragma unroll
    for (int ks = 0; ks < 8; ++ks) {
      const bf16x8 af = *(const bf16x8*)&Ew[w][col][ks * 32 + quad * 8];
      #pragma unroll
      for (int hb = 0; hb < 8; ++hb) {
        const bf16x8 bfv = *(const bf16x8*)(We + (size_t)(hb * 16 + col) * 256 + ks * 32 + quad * 8);
        acc[hb] = MFMA16x16(af, bfv, acc[hb]);
      }
    }
    float h[8][4];
    float lg[4] = {0.f, 0.f, 0.f, 0.f};
    #pragma unroll
    for (int hb = 0; hb < 8; ++hb) {
      const int hc = hb * 16 + col;
      const float ss = s1[hc], tt = t1[hc], ww = wat[hc];
      #pragma unroll
      for (int r = 0; r < 4; ++r) {
        const float hv = fmaxf(acc[hb][r] * ss + tt, 0.f);
        h[hb][r] = hv;
        lg[r] += hv * ww;
      }
    }
    #pragma unroll
    for (int r = 0; r < 4; ++r) {
      float vv = lg[r];
      vv += __shfl_xor(vv, 1);
      vv += __shfl_xor(vv, 2);
      vv += __shfl_xor(vv, 4);
      vv += __shfl_xor(vv, 8);
      lg[r] = vv;
    }
    float mx = fmaxf(fmaxf(lg[0], lg[1]), fmaxf(lg[2], lg[3]));
    mx = fmaxf(mx, __shfl_xor(mx, 16));
    mx = fmaxf(mx, __shfl_xor(mx, 32));
    float ex[4];
    float sm = 0.f;
    #pragma unroll
    for (int r = 0; r < 4; ++r) { ex[r] = expf(lg[r] - mx); sm += ex[r]; }
    sm += __shfl_xor(sm, 16);
    sm += __shfl_xor(sm, 32);
    const float inv = 1.0f / sm;
    float ag[8];
    #pragma unroll
    for (int hb = 0; hb < 8; ++hb) {
      float a = h[hb][0] * ex[0] + h[hb][1] * ex[1] + h[hb][2] * ex[2] + h[hb][3] * ex[3];
      a += __shfl_xor(a, 16);
      a += __shfl_xor(a, 32);
      ag[hb] = a * inv;
    }
    if (quad == 0) {
      bf16* ao = agg + (size_t)p * HED;
      #pragma unroll
      for (int hb = 0; hb < 8; ++hb) ao[hb * 16 + col] = (bf16)ag[hb];
    }
    __syncthreads();
  }
}

// ---------------------------------------------------------------------------
// K3: fuse GEMM (B*N,128)x(128,256) + bn2 + relu -> outp bf16
// ---------------------------------------------------------------------------
__global__ __launch_bounds__(256) void k_fuse(const bf16* __restrict__ agg,
                                              const bf16* __restrict__ Wf,
                                              const float* __restrict__ g2, const float* __restrict__ b2,
                                              const float* __restrict__ m2, const float* __restrict__ v2,
                                              bf16* __restrict__ outp) {
  const int tid  = threadIdx.x;
  const int w    = tid >> 6;
  const int lane = tid & 63;
  const int col  = lane & 15;
  const int quad = lane >> 4;
  const int p0   = (blockIdx.x * 4 + w) * 16;
  bf16x8 afr[4];
  const bf16* arow = agg + (size_t)(p0 + col) * HED + quad * 8;
  #pragma unroll
  for (int ks = 0; ks < 4; ++ks) afr[ks] = *(const bf16x8*)(arow + ks * 32);
  #pragma unroll
  for (int ob = 0; ob < 16; ++ob) {
    f32x4 acc = {0.f, 0.f, 0.f, 0.f};
    const bf16* brow = Wf + (size_t)(ob * 16 + col) * HED + quad * 8;
    #pragma unroll
    for (int ks = 0; ks < 4; ++ks)
      acc = MFMA16x16(afr[ks], *(const bf16x8*)(brow + ks * 32), acc);
    const int o = ob * 16 + col;
    const float ss = g2[o] / sqrtf(v2[o] + 1e-5f);
    const float tt = b2[o] - m2[o] * ss;
    #pragma unroll
    for (int r = 0; r < 4; ++r) {
      outp[(size_t)(p0 + quad * 4 + r) * COUT + o] = (bf16)fmaxf(acc[r] * ss + tt, 0.f);
    }
  }
}

// ---------------------------------------------------------------------------
// K4: SE. One block per (b, chunk): mean over 256 pts -> fc1+relu -> fc2+sigmoid
// ---------------------------------------------------------------------------
__global__ __launch_bounds__(256) void k_se(const bf16* __restrict__ outp,
                                            const float* __restrict__ f1w, const float* __restrict__ f1b,
                                            const float* __restrict__ f2w, const float* __restrict__ f2b,
                                            float* __restrict__ sse) {
  __shared__ float mean_s[COUT];
  __shared__ float h1[64];
  const int bc  = blockIdx.x;   // b*16 + chunk
  const int tid = threadIdx.x;
  const bf16* base = outp + (size_t)bc * 256 * COUT;
  float s = 0.f;
  for (int p2 = 0; p2 < 256; ++p2) s += (float)base[(size_t)p2 * COUT + tid];
  mean_s[tid] = s * (1.0f / 256.0f);
  __syncthreads();
  if (tid < 64) {
    float a = f1b[tid];
    for (int c = 0; c < COUT; ++c) a += f1w[tid * COUT + c] * mean_s[c];
    h1[tid] = fmaxf(a, 0.f);
  }
  __syncthreads();
  float a = f2b[tid];
  #pragma unroll
  for (int j = 0; j < 64; ++j) a += f2w[tid * 64 + j] * h1[j];
  sse[(size_t)bc * COUT + tid] = 1.0f / (1.0f + expf(-a));
}

// ---------------------------------------------------------------------------
// K5: residual GEMM + bn3; out = outp*se + res, fp32, transposed (B,Cout,N)
// ---------------------------------------------------------------------------
__global__ __launch_bounds__(256) void k_final(const bf16* __restrict__ xh,
                                               const bf16* __restrict__ Wr,
                                               const float* __restrict__ g3, const float* __restrict__ b3,
                                               const float* __restrict__ m3, const float* __restrict__ v3,
                                               const bf16* __restrict__ outp,
                                               const float* __restrict__ sse,
                                               float* __restrict__ out) {
  const int tid  = threadIdx.x;
  const int w    = tid >> 6;
  const int lane = tid & 63;
  const int col  = lane & 15;
  const int quad = lane >> 4;
  const int p0   = (blockIdx.x * 4 + w) * 16;
  const int b    = p0 >> 12;
  const int n0l  = p0 & 4095;
  bf16x8 afr[4];
  const bf16* arow = xh + (size_t)(p0 + col) * CIN + quad * 8;
  #pragma unroll
  for (int ks = 0; ks < 4; ++ks) afr[ks] = *(const bf16x8*)(arow + ks * 32);
  const float* scb = sse + (size_t)(b * 16 + (n0l >> 8)) * COUT;
  #pragma unroll
  for (int ob = 0; ob < 16; ++ob) {
    f32x4 acc = {0.f, 0.f, 0.f, 0.f};
    const bf16* brow = Wr + (size_t)(ob * 16 + col) * CIN + quad * 8;
    #pragma unroll
    for (int ks = 0; ks < 4; ++ks)
      acc = MFMA16x16(afr[ks], *(const bf16x8*)(brow + ks * 32), acc);
    const int o = ob * 16 + col;
    const float ss = g3[o] / sqrtf(v3[o] + 1e-5f);
    const float tt = b3[o] - m3[o] * ss;
    const float sc = scb[o];
    f32x4 pk;
    #pragma unroll
    for (int r = 0; r < 4; ++r) {
      const float res = acc[r] * ss + tt;
      pk[r] = (float)outp[(size_t)(p0 + quad * 4 + r) * COUT + o] * sc + res;
    }
    float* op = out + (size_t)(b * COUT + o) * NPT + n0l + quad * 4;
    *(f32x4*)op = pk;
  }
}

// ---------------------------------------------------------------------------
extern "C" void kernel_launch(void* const* d_in, const int* in_sizes, int n_in,
                              void* d_out, int out_size, void* d_ws, size_t ws_size,
                              hipStream_t stream) {
  (void)in_sizes; (void)n_in; (void)out_size; (void)ws_size;
  const float* x    = (const float*)d_in[0];
  const float* We   = (const float*)d_in[1];
  const float* g1   = (const float*)d_in[2];
  const float* b1   = (const float*)d_in[3];
  const float* m1   = (const float*)d_in[4];
  const float* v1   = (const float*)d_in[5];
  const float* watt = (const float*)d_in[6];
  const float* Wf   = (const float*)d_in[7];
  const float* g2   = (const float*)d_in[8];
  const float* b2   = (const float*)d_in[9];
  const float* m2   = (const float*)d_in[10];
  const float* v2   = (const float*)d_in[11];
  const float* f1w  = (const float*)d_in[12];
  const float* f1b  = (const float*)d_in[13];
  const float* f2w  = (const float*)d_in[14];
  const float* f2b  = (const float*)d_in[15];
  const float* Wr   = (const float*)d_in[16];
  const float* g3   = (const float*)d_in[17];
  const float* b3   = (const float*)d_in[18];
  const float* m3   = (const float*)d_in[19];
  const float* v3   = (const float*)d_in[20];

  char* ws = (char*)d_ws;
  size_t off = 0;
  bf16*  xth  = (bf16*)(ws + off);  off += (size_t)BB * NPT * CIN * 2;        // 4 MB
  bf16*  xtl  = (bf16*)(ws + off);  off += (size_t)BB * NPT * CIN * 2;        // 4 MB
  float* sq   = (float*)(ws + off); off += (size_t)BB * NPT * 4;              // 64 KB
  int*   idxp = (int*)(ws + off);   off += (size_t)BB * NPT * KNBR * 4;       // 1 MB
  bf16*  aggp = (bf16*)(ws + off);  off += (size_t)BB * NPT * HED * 2;        // 4 MB
  bf16*  outp = (bf16*)(ws + off);  off += (size_t)BB * NPT * COUT * 2;       // 8 MB
  float* ssep = (float*)(ws + off); off += (size_t)BB * 16 * COUT * 4;        // 64 KB
  bf16*  Web  = (bf16*)(ws + off);  off += (size_t)HED * 2 * CIN * 2;         // 64 KB
  bf16*  Wfb  = (bf16*)(ws + off);  off += (size_t)COUT * HED * 2;            // 64 KB
  bf16*  Wrb  = (bf16*)(ws + off);  off += (size_t)COUT * CIN * 2;            // 64 KB

  float* out = (float*)d_out;

  k_wconv<<<384, 256, 0, stream>>>(We, Wf, Wr, Web, Wfb, Wrb);
  k_prep<<<256, 256, 0, stream>>>(x, xth, xtl, sq);
  k_knn<<<256, 256, 0, stream>>>(xth, xtl, sq, idxp);
  k_edge<<<1024, 256, 0, stream>>>(xth, xtl, idxp, Web, g1, b1, m1, v1, watt, aggp);
  k_fuse<<<256, 256, 0, stream>>>(aggp, Wfb, g2, b2, m2, v2, outp);
  k_se<<<64, 256, 0, stream>>>(outp, f1w, f1b, f2w, f2b, ssep);
  k_final<<<256, 256, 0, stream>>>(xth, Wrb, g3, b3, m3, v3, outp, ssep, out);
}

// Round 3
// 723.185 us; speedup vs baseline: 1.9998x; 1.9998x over previous
//
#include <hip/hip_runtime.h>
#include <cstddef>

typedef __bf16 bf16;
typedef __bf16 bf16x8 __attribute__((ext_vector_type(8)));
typedef float  f32x4  __attribute__((ext_vector_type(4)));
typedef unsigned short u16;

#define MFMA16x16(a, b, c) __builtin_amdgcn_mfma_f32_16x16x32_bf16((a), (b), (c), 0, 0, 0)

namespace {
constexpr int BB   = 4;     // batch
constexpr int CIN  = 128;   // input channels
constexpr int NPT  = 4096;  // points
constexpr int KNBR = 16;    // neighbors
constexpr int HED  = 128;   // hidden (edge mlp out)
constexpr int COUT = 256;   // output channels
}

// ---------------------------------------------------------------------------
// W0: convert the three GEMM weight matrices fp32 -> bf16 (each 32768 elems)
// ---------------------------------------------------------------------------
__global__ __launch_bounds__(256) void k_wconv(const float* __restrict__ We,
                                               const float* __restrict__ Wf,
                                               const float* __restrict__ Wr,
                                               bf16* __restrict__ Web,
                                               bf16* __restrict__ Wfb,
                                               bf16* __restrict__ Wrb) {
  const int i = blockIdx.x * 256 + threadIdx.x;   // [0, 3*32768)
  const int a = i >> 15;
  const int j = i & 32767;
  const float* src = (a == 0) ? We : (a == 1) ? Wf : Wr;
  bf16*        dst = (a == 0) ? Web : (a == 1) ? Wfb : Wrb;
  dst[j] = (bf16)src[j];
}

// ---------------------------------------------------------------------------
// K0: transpose x (B,Cin,N) fp32 -> xt_hi/xt_lo (B,N,Cin) bf16 split, and
//     sq[b][n] = sum_c x^2 in fp32 (matches reference's fp32 sq).
// ---------------------------------------------------------------------------
__global__ __launch_bounds__(256) void k_prep(const float* __restrict__ x,
                                              bf16* __restrict__ xh,
                                              bf16* __restrict__ xl,
                                              float* __restrict__ sq) {
  __shared__ __attribute__((aligned(16))) bf16 th[64][136];
  __shared__ __attribute__((aligned(16))) bf16 tl[64][136];
  __shared__ float sqp[4][64];
  const int tid = threadIdx.x;
  const int b   = blockIdx.x >> 6;
  const int n0  = (blockIdx.x & 63) << 6;
  const int nl  = tid & 63;
  const int cg  = tid >> 6;
  const float* xb = x + (size_t)b * CIN * NPT;
  float acc = 0.f;
  #pragma unroll
  for (int rep = 0; rep < 32; ++rep) {
    const int c = rep * 4 + cg;
    const float v = xb[(size_t)c * NPT + n0 + nl];
    const bf16 h = (bf16)v;
    const bf16 l = (bf16)(v - (float)h);
    acc += v * v;
    th[nl][c] = h;
    tl[nl][c] = l;
  }
  sqp[cg][nl] = acc;
  __syncthreads();
  bf16* xho = xh + ((size_t)b * NPT + n0) * CIN;
  bf16* xlo = xl + ((size_t)b * NPT + n0) * CIN;
  #pragma unroll
  for (int rep = 0; rep < 32; ++rep) {
    const int e = rep * 256 + tid;
    const int r = e >> 7;
    const int c = e & 127;
    xho[(size_t)r * CIN + c] = th[r][c];
    xlo[(size_t)r * CIN + c] = tl[r][c];
  }
  if (tid < 64) {
    sq[b * NPT + n0 + tid] = sqp[0][tid] + sqp[1][tid] + sqp[2][tid] + sqp[3][tid];
  }
}

// ---------------------------------------------------------------------------
// K1: KNN, register-resident distances.
// Block = 256 (4 waves) covering 32 queries; wave w scans candidate range
// [w*1024, w*1024+1024). MFMA with A=candidates, B=queries puts Gram values in
// each lane's accumulator (row = candidate, col = query) -> no LDS round-trip,
// no barriers in the hot loop. Each lane keeps two top-16 insertion lists
// (one per 16-query subtile). Final: 16 sorted lists/query dumped to LDS,
// 32 lanes do a lexicographic (d, idx) top-16 over 256 entries -> exact
// lax.top_k tie semantics (candidate ranges disjoint; set-level exactness).
// Split-bf16 (hh+hl+lh) preserved: d2 err ~1e-4 << rank-16/17 gap.
// ---------------------------------------------------------------------------
__global__ __launch_bounds__(256) void k_knn(const bf16* __restrict__ xh,
                                             const bf16* __restrict__ xl,
                                             const float* __restrict__ sq,
                                             int* __restrict__ knn_idx) {
  __shared__ float Ld[32][256];   // 32 KB
  __shared__ int   Li[32][256];   // 32 KB
  const int tid  = threadIdx.x;
  const int w    = tid >> 6;
  const int lane = tid & 63;
  const int col  = lane & 15;
  const int quad = lane >> 4;
  const int b    = blockIdx.x >> 7;          // 128 blocks per batch
  const int q0   = (blockIdx.x & 127) << 5;  // 32 queries per block
  const bf16*  xhb = xh + (size_t)b * NPT * CIN;
  const bf16*  xlb = xl + (size_t)b * NPT * CIN;
  const float* sqb = sq + b * NPT;

  // query fragments (B operand), 2 subtiles of 16 queries
  bf16x8 qh[2][4], ql[2][4];
  float sqn[2];
  #pragma unroll
  for (int t = 0; t < 2; ++t) {
    const bf16* qrh = xhb + (size_t)(q0 + t * 16 + col) * CIN + quad * 8;
    const bf16* qrl = xlb + (size_t)(q0 + t * 16 + col) * CIN + quad * 8;
    #pragma unroll
    for (int ks = 0; ks < 4; ++ks) {
      qh[t][ks] = *(const bf16x8*)(qrh + ks * 32);
      ql[t][ks] = *(const bf16x8*)(qrl + ks * 32);
    }
    sqn[t] = sqb[q0 + t * 16 + col];
  }

  float bd[2][16];
  int   bi[2][16];
  #pragma unroll
  for (int t = 0; t < 2; ++t)
    #pragma unroll
    for (int i = 0; i < 16; ++i) { bd[t][i] = 3.4028235e38f; bi[t][i] = 0x7fffffff; }

  const int cbase = w << 10;
  for (int mt = 0; mt < 16; ++mt) {
    const int m0 = cbase + (mt << 6);
    #pragma unroll
    for (int cb = 0; cb < 4; ++cb) {
      const bf16* crh = xhb + (size_t)(m0 + cb * 16 + col) * CIN + quad * 8;
      const bf16* crl = xlb + (size_t)(m0 + cb * 16 + col) * CIN + quad * 8;
      f32x4 a0 = {0.f, 0.f, 0.f, 0.f};
      f32x4 a1 = {0.f, 0.f, 0.f, 0.f};
      #pragma unroll
      for (int ks = 0; ks < 4; ++ks) {
        const bf16x8 ch_ = *(const bf16x8*)(crh + ks * 32);
        const bf16x8 cl_ = *(const bf16x8*)(crl + ks * 32);
        a0 = MFMA16x16(cl_, qh[0][ks], a0);
        a0 = MFMA16x16(ch_, ql[0][ks], a0);
        a0 = MFMA16x16(ch_, qh[0][ks], a0);
        a1 = MFMA16x16(cl_, qh[1][ks], a1);
        a1 = MFMA16x16(ch_, ql[1][ks], a1);
        a1 = MFMA16x16(ch_, qh[1][ks], a1);
      }
      const f32x4 sqm = *(const f32x4*)(sqb + m0 + cb * 16 + quad * 4);
      #pragma unroll
      for (int r = 0; r < 4; ++r) {
        const int m = m0 + cb * 16 + quad * 4 + r;
        {
          const float d = (sqn[0] + sqm[r]) - 2.0f * a0[r];
          if (d < bd[0][15]) {
            float cd = d; int cm = m; bool ins = false;
            #pragma unroll
            for (int i = 0; i < 16; ++i) {
              const bool tk = ins || (cd < bd[0][i]);
              if (tk) {
                const float td = bd[0][i]; const int ti = bi[0][i];
                bd[0][i] = cd; bi[0][i] = cm; cd = td; cm = ti; ins = true;
              }
            }
          }
        }
        {
          const float d = (sqn[1] + sqm[r]) - 2.0f * a1[r];
          if (d < bd[1][15]) {
            float cd = d; int cm = m; bool ins = false;
            #pragma unroll
            for (int i = 0; i < 16; ++i) {
              const bool tk = ins || (cd < bd[1][i]);
              if (tk) {
                const float td = bd[1][i]; const int ti = bi[1][i];
                bd[1][i] = cd; bi[1][i] = cm; cd = td; cm = ti; ins = true;
              }
            }
          }
        }
      }
    }
  }

  // dump per-lane sorted lists: query q = t*16+col, list = w*4+quad
  const int listid = (w << 2) | quad;
  #pragma unroll
  for (int t = 0; t < 2; ++t) {
    const int q = (t << 4) | col;
    #pragma unroll
    for (int i = 0; i < 16; ++i) {
      Ld[q][listid * 16 + i] = bd[t][i];
      Li[q][listid * 16 + i] = bi[t][i];
    }
  }
  __syncthreads();

  // final merge: 32 lanes, one query each, lexicographic (d, idx) top-16
  if (tid < 32) {
    float fd[16]; int fi[16];
    #pragma unroll
    for (int i = 0; i < 16; ++i) { fd[i] = 3.4028235e38f; fi[i] = 0x7fffffff; }
    for (int e = 0; e < 256; ++e) {
      const float d = Ld[tid][e];
      const int  id = Li[tid][e];
      if ((d < fd[15]) || (d == fd[15] && id < fi[15])) {
        float cd = d; int cm = id; bool ins = false;
        #pragma unroll
        for (int i = 0; i < 16; ++i) {
          const bool tk = ins || (cd < fd[i]) || (cd == fd[i] && cm < fi[i]);
          if (tk) {
            const float td = fd[i]; const int ti = fi[i];
            fd[i] = cd; fi[i] = cm; cd = td; cm = ti; ins = true;
          }
        }
      }
    }
    int* op = knn_idx + (size_t)(b * NPT + q0 + tid) * KNBR;
    #pragma unroll
    for (int i = 0; i < 16; ++i) op[i] = fi[i];
  }
}

// ---------------------------------------------------------------------------
// K2: edge MLP + attention + aggregate. One wave per point, 4 points per wave.
// Gathers hi+lo, reconstructs fp32, builds edge=[neigh-center, center] in LDS
// as bf16 (single rounding). h kept in fp32 registers; softmax + aggregate via
// shfl_xor reductions.
// ---------------------------------------------------------------------------
__global__ __launch_bounds__(256) void k_edge(const bf16* __restrict__ xh,
                                              const bf16* __restrict__ xl,
                                              const int* __restrict__ knn_idx,
                                              const bf16* __restrict__ We,
                                              const float* __restrict__ g1, const float* __restrict__ b1,
                                              const float* __restrict__ m1, const float* __restrict__ v1,
                                              const float* __restrict__ watt,
                                              bf16* __restrict__ agg) {
  __shared__ __attribute__((aligned(16))) bf16 Ew[4][16][264];
  __shared__ float s1[HED], t1[HED], wat[HED];
  const int tid  = threadIdx.x;
  const int w    = tid >> 6;
  const int lane = tid & 63;
  const int col  = lane & 15;
  const int quad = lane >> 4;
  if (tid < HED) {
    const float ss = g1[tid] / sqrtf(v1[tid] + 1e-5f);
    s1[tid] = ss;
    t1[tid] = b1[tid] - m1[tid] * ss;
    wat[tid] = watt[tid];
  }
  __syncthreads();
  const int gw = blockIdx.x * 4 + w;
  for (int it = 0; it < 4; ++it) {
    const int p = gw * 4 + it;
    const int b = p >> 12;
    const int n = p & 4095;
    const bf16* xhb = xh + (size_t)b * NPT * CIN;
    const bf16* xlb = xl + (size_t)b * NPT * CIN;
    const int my = knn_idx[(size_t)p * KNBR + col];
    const int m  = __shfl(my, lane >> 2);
    const int sub = lane & 3;
    const int kn  = lane >> 2;
    const bf16* nh = xhb + (size_t)m * CIN + sub * 32;
    const bf16* nl_ = xlb + (size_t)m * CIN + sub * 32;
    const bf16* ch = xhb + (size_t)n * CIN + sub * 32;
    const bf16* cl = xlb + (size_t)n * CIN + sub * 32;
    #pragma unroll
    for (int j = 0; j < 4; ++j) {
      const bf16x8 nhv = *(const bf16x8*)(nh + j * 8);
      const bf16x8 nlv = *(const bf16x8*)(nl_ + j * 8);
      const bf16x8 chv = *(const bf16x8*)(ch + j * 8);
      const bf16x8 clv = *(const bf16x8*)(cl + j * 8);
      bf16x8 dv, cv;
      #pragma unroll
      for (int e = 0; e < 8; ++e) {
        const float nf = (float)nhv[e] + (float)nlv[e];
        const float cf = (float)chv[e] + (float)clv[e];
        dv[e] = (bf16)(nf - cf);
        cv[e] = (bf16)cf;
      }
      *(bf16x8*)&Ew[w][kn][sub * 32 + j * 8]       = dv;
      *(bf16x8*)&Ew[w][kn][128 + sub * 32 + j * 8] = cv;
    }
    __syncthreads();
    const f32x4 zero4 = {0.f, 0.f, 0.f, 0.f};
    f32x4 acc[8];
    #pragma unroll
    for (int hb = 0; hb < 8; ++hb) acc[hb] = zero4;
    #pragma unroll
    for (int ks = 0; ks < 8; ++ks) {
      const bf16x8 af = *(const bf16x8*)&Ew[w][col][ks * 32 + quad * 8];
      #pragma unroll
      for (int hb = 0; hb < 8; ++hb) {
        const bf16x8 bfv = *(const bf16x8*)(We + (size_t)(hb * 16 + col) * 256 + ks * 32 + quad * 8);
        acc[hb] = MFMA16x16(af, bfv, acc[hb]);
      }
    }
    float h[8][4];
    float lg[4] = {0.f, 0.f, 0.f, 0.f};
    #pragma unroll
    for (int hb = 0; hb < 8; ++hb) {
      const int hc = hb * 16 + col;
      const float ss = s1[hc], tt = t1[hc], ww = wat[hc];
      #pragma unroll
      for (int r = 0; r < 4; ++r) {
        const float hv = fmaxf(acc[hb][r] * ss + tt, 0.f);
        h[hb][r] = hv;
        lg[r] += hv * ww;
      }
    }
    #pragma unroll
    for (int r = 0; r < 4; ++r) {
      float vv = lg[r];
      vv += __shfl_xor(vv, 1);
      vv += __shfl_xor(vv, 2);
      vv += __shfl_xor(vv, 4);
      vv += __shfl_xor(vv, 8);
      lg[r] = vv;
    }
    float mx = fmaxf(fmaxf(lg[0], lg[1]), fmaxf(lg[2], lg[3]));
    mx = fmaxf(mx, __shfl_xor(mx, 16));
    mx = fmaxf(mx, __shfl_xor(mx, 32));
    float ex[4];
    float sm = 0.f;
    #pragma unroll
    for (int r = 0; r < 4; ++r) { ex[r] = expf(lg[r] - mx); sm += ex[r]; }
    sm += __shfl_xor(sm, 16);
    sm += __shfl_xor(sm, 32);
    const float inv = 1.0f / sm;
    float ag[8];
    #pragma unroll
    for (int hb = 0; hb < 8; ++hb) {
      float a = h[hb][0] * ex[0] + h[hb][1] * ex[1] + h[hb][2] * ex[2] + h[hb][3] * ex[3];
      a += __shfl_xor(a, 16);
      a += __shfl_xor(a, 32);
      ag[hb] = a * inv;
    }
    if (quad == 0) {
      bf16* ao = agg + (size_t)p * HED;
      #pragma unroll
      for (int hb = 0; hb < 8; ++hb) ao[hb * 16 + col] = (bf16)ag[hb];
    }
    __syncthreads();
  }
}

// ---------------------------------------------------------------------------
// K3: fuse GEMM (B*N,128)x(128,256) + bn2 + relu -> outp bf16
// ---------------------------------------------------------------------------
__global__ __launch_bounds__(256) void k_fuse(const bf16* __restrict__ agg,
                                              const bf16* __restrict__ Wf,
                                              const float* __restrict__ g2, const float* __restrict__ b2,
                                              const float* __restrict__ m2, const float* __restrict__ v2,
                                              bf16* __restrict__ outp) {
  const int tid  = threadIdx.x;
  const int w    = tid >> 6;
  const int lane = tid & 63;
  const int col  = lane & 15;
  const int quad = lane >> 4;
  const int p0   = (blockIdx.x * 4 + w) * 16;
  bf16x8 afr[4];
  const bf16* arow = agg + (size_t)(p0 + col) * HED + quad * 8;
  #pragma unroll
  for (int ks = 0; ks < 4; ++ks) afr[ks] = *(const bf16x8*)(arow + ks * 32);
  #pragma unroll
  for (int ob = 0; ob < 16; ++ob) {
    f32x4 acc = {0.f, 0.f, 0.f, 0.f};
    const bf16* brow = Wf + (size_t)(ob * 16 + col) * HED + quad * 8;
    #pragma unroll
    for (int ks = 0; ks < 4; ++ks)
      acc = MFMA16x16(afr[ks], *(const bf16x8*)(brow + ks * 32), acc);
    const int o = ob * 16 + col;
    const float ss = g2[o] / sqrtf(v2[o] + 1e-5f);
    const float tt = b2[o] - m2[o] * ss;
    #pragma unroll
    for (int r = 0; r < 4; ++r) {
      outp[(size_t)(p0 + quad * 4 + r) * COUT + o] = (bf16)fmaxf(acc[r] * ss + tt, 0.f);
    }
  }
}

// ---------------------------------------------------------------------------
// K4: SE. One block per (b, chunk): mean over 256 pts -> fc1+relu -> fc2+sigmoid
// ---------------------------------------------------------------------------
__global__ __launch_bounds__(256) void k_se(const bf16* __restrict__ outp,
                                            const float* __restrict__ f1w, const float* __restrict__ f1b,
                                            const float* __restrict__ f2w, const float* __restrict__ f2b,
                                            float* __restrict__ sse) {
  __shared__ float mean_s[COUT];
  __shared__ float h1[64];
  const int bc  = blockIdx.x;   // b*16 + chunk
  const int tid = threadIdx.x;
  const bf16* base = outp + (size_t)bc * 256 * COUT;
  float s = 0.f;
  for (int p2 = 0; p2 < 256; ++p2) s += (float)base[(size_t)p2 * COUT + tid];
  mean_s[tid] = s * (1.0f / 256.0f);
  __syncthreads();
  if (tid < 64) {
    float a = f1b[tid];
    for (int c = 0; c < COUT; ++c) a += f1w[tid * COUT + c] * mean_s[c];
    h1[tid] = fmaxf(a, 0.f);
  }
  __syncthreads();
  float a = f2b[tid];
  #pragma unroll
  for (int j = 0; j < 64; ++j) a += f2w[tid * 64 + j] * h1[j];
  sse[(size_t)bc * COUT + tid] = 1.0f / (1.0f + expf(-a));
}

// ---------------------------------------------------------------------------
// K5: residual GEMM + bn3; out = outp*se + res, fp32, transposed (B,Cout,N)
// ---------------------------------------------------------------------------
__global__ __launch_bounds__(256) void k_final(const bf16* __restrict__ xh,
                                               const bf16* __restrict__ Wr,
                                               const float* __restrict__ g3, const float* __restrict__ b3,
                                               const float* __restrict__ m3, const float* __restrict__ v3,
                                               const bf16* __restrict__ outp,
                                               const float* __restrict__ sse,
                                               float* __restrict__ out) {
  const int tid  = threadIdx.x;
  const int w    = tid >> 6;
  const int lane = tid & 63;
  const int col  = lane & 15;
  const int quad = lane >> 4;
  const int p0   = (blockIdx.x * 4 + w) * 16;
  const int b    = p0 >> 12;
  const int n0l  = p0 & 4095;
  bf16x8 afr[4];
  const bf16* arow = xh + (size_t)(p0 + col) * CIN + quad * 8;
  #pragma unroll
  for (int ks = 0; ks < 4; ++ks) afr[ks] = *(const bf16x8*)(arow + ks * 32);
  const float* scb = sse + (size_t)(b * 16 + (n0l >> 8)) * COUT;
  #pragma unroll
  for (int ob = 0; ob < 16; ++ob) {
    f32x4 acc = {0.f, 0.f, 0.f, 0.f};
    const bf16* brow = Wr + (size_t)(ob * 16 + col) * CIN + quad * 8;
    #pragma unroll
    for (int ks = 0; ks < 4; ++ks)
      acc = MFMA16x16(afr[ks], *(const bf16x8*)(brow + ks * 32), acc);
    const int o = ob * 16 + col;
    const float ss = g3[o] / sqrtf(v3[o] + 1e-5f);
    const float tt = b3[o] - m3[o] * ss;
    const float sc = scb[o];
    f32x4 pk;
    #pragma unroll
    for (int r = 0; r < 4; ++r) {
      const float res = acc[r] * ss + tt;
      pk[r] = (float)outp[(size_t)(p0 + quad * 4 + r) * COUT + o] * sc + res;
    }
    float* op = out + (size_t)(b * COUT + o) * NPT + n0l + quad * 4;
    *(f32x4*)op = pk;
  }
}

// ---------------------------------------------------------------------------
extern "C" void kernel_launch(void* const* d_in, const int* in_sizes, int n_in,
                              void* d_out, int out_size, void* d_ws, size_t ws_size,
                              hipStream_t stream) {
  (void)in_sizes; (void)n_in; (void)out_size; (void)ws_size;
  const float* x    = (const float*)d_in[0];
  const float* We   = (const float*)d_in[1];
  const float* g1   = (const float*)d_in[2];
  const float* b1   = (const float*)d_in[3];
  const float* m1   = (const float*)d_in[4];
  const float* v1   = (const float*)d_in[5];
  const float* watt = (const float*)d_in[6];
  const float* Wf   = (const float*)d_in[7];
  const float* g2   = (const float*)d_in[8];
  const float* b2   = (const float*)d_in[9];
  const float* m2   = (const float*)d_in[10];
  const float* v2   = (const float*)d_in[11];
  const float* f1w  = (const float*)d_in[12];
  const float* f1b  = (const float*)d_in[13];
  const float* f2w  = (const float*)d_in[14];
  const float* f2b  = (const float*)d_in[15];
  const float* Wr   = (const float*)d_in[16];
  const float* g3   = (const float*)d_in[17];
  const float* b3   = (const float*)d_in[18];
  const float* m3   = (const float*)d_in[19];
  const float* v3   = (const float*)d_in[20];

  char* ws = (char*)d_ws;
  size_t off = 0;
  bf16*  xth  = (bf16*)(ws + off);  off += (size_t)BB * NPT * CIN * 2;        // 4 MB
  bf16*  xtl  = (bf16*)(ws + off);  off += (size_t)BB * NPT * CIN * 2;        // 4 MB
  float* sq   = (float*)(ws + off); off += (size_t)BB * NPT * 4;              // 64 KB
  int*   idxp = (int*)(ws + off);   off += (size_t)BB * NPT * KNBR * 4;       // 1 MB
  bf16*  aggp = (bf16*)(ws + off);  off += (size_t)BB * NPT * HED * 2;        // 4 MB
  bf16*  outp = (bf16*)(ws + off);  off += (size_t)BB * NPT * COUT * 2;       // 8 MB
  float* ssep = (float*)(ws + off); off += (size_t)BB * 16 * COUT * 4;        // 64 KB
  bf16*  Web  = (bf16*)(ws + off);  off += (size_t)HED * 2 * CIN * 2;         // 64 KB
  bf16*  Wfb  = (bf16*)(ws + off);  off += (size_t)COUT * HED * 2;            // 64 KB
  bf16*  Wrb  = (bf16*)(ws + off);  off += (size_t)COUT * CIN * 2;            // 64 KB

  float* out = (float*)d_out;

  k_wconv<<<384, 256, 0, stream>>>(We, Wf, Wr, Web, Wfb, Wrb);
  k_prep<<<256, 256, 0, stream>>>(x, xth, xtl, sq);
  k_knn<<<512, 256, 0, stream>>>(xth, xtl, sq, idxp);
  k_edge<<<1024, 256, 0, stream>>>(xth, xtl, idxp, Web, g1, b1, m1, v1, watt, aggp);
  k_fuse<<<256, 256, 0, stream>>>(aggp, Wfb, g2, b2, m2, v2, outp);
  k_se<<<64, 256, 0, stream>>>(outp, f1w, f1b, f2w, f2b, ssep);
  k_final<<<256, 256, 0, stream>>>(xth, Wrb, g3, b3, m3, v3, outp, ssep, out);
}

// Round 4
// 429.993 us; speedup vs baseline: 3.3634x; 1.6819x over previous
//
#include <hip/hip_runtime.h>
#include <cstddef>

typedef __bf16 bf16;
typedef __bf16 bf16x8 __attribute__((ext_vector_type(8)));
typedef float  f32x4  __attribute__((ext_vector_type(4)));
typedef unsigned short u16;
typedef unsigned long long u64;

#define MFMA16x16(a, b, c) __builtin_amdgcn_mfma_f32_16x16x32_bf16((a), (b), (c), 0, 0, 0)

namespace {
constexpr int BB   = 4;     // batch
constexpr int CIN  = 128;   // input channels
constexpr int NPT  = 4096;  // points
constexpr int KNBR = 16;    // neighbors
constexpr int HED  = 128;   // hidden (edge mlp out)
constexpr int COUT = 256;   // output channels
}

// ordered-float transform: monotone uint32 over all finite floats
__device__ __forceinline__ unsigned int ord_f32(float f) {
  unsigned int b = __float_as_uint(f);
  return b ^ (0x80000000u | (unsigned int)((int)b >> 31));
}
__device__ __forceinline__ u64 mk_key(float d, int m) {
  return ((u64)ord_f32(d) << 32) | (unsigned int)m;
}

// branch-free bitonic sort of 16 u64 keys, ascending
__device__ __forceinline__ void sort16(u64* k) {
  #pragma unroll
  for (int sz = 2; sz <= 16; sz <<= 1) {
    #pragma unroll
    for (int st = sz >> 1; st > 0; st >>= 1) {
      #pragma unroll
      for (int i = 0; i < 16; ++i) {
        const int j = i ^ st;
        if (j > i) {
          const bool up = ((i & sz) == 0);
          const u64 a = k[i], c = k[j];
          const bool sw = up ? (a > c) : (a < c);
          k[i] = sw ? c : a;
          k[j] = sw ? a : c;
        }
      }
    }
  }
}

// R (sorted asc 16) <- lowest 16 of R ∪ B (B sorted asc), sorted asc
__device__ __forceinline__ void merge16(u64* R, const u64* B) {
  u64 t[16];
  #pragma unroll
  for (int i = 0; i < 16; ++i) {
    const u64 a = R[i], c = B[15 - i];
    t[i] = (a < c) ? a : c;          // half-cleaner: lower half, bitonic
  }
  #pragma unroll
  for (int st = 8; st > 0; st >>= 1) {
    #pragma unroll
    for (int i = 0; i < 16; ++i) {
      const int j = i ^ st;
      if (j > i) {
        const u64 a = t[i], c = t[j];
        const bool sw = a > c;
        t[i] = sw ? c : a;
        t[j] = sw ? a : c;
      }
    }
  }
  #pragma unroll
  for (int i = 0; i < 16; ++i) R[i] = t[i];
}

// ---------------------------------------------------------------------------
// W0: convert the three GEMM weight matrices fp32 -> bf16 (each 32768 elems)
// ---------------------------------------------------------------------------
__global__ __launch_bounds__(256) void k_wconv(const float* __restrict__ We,
                                               const float* __restrict__ Wf,
                                               const float* __restrict__ Wr,
                                               bf16* __restrict__ Web,
                                               bf16* __restrict__ Wfb,
                                               bf16* __restrict__ Wrb) {
  const int i = blockIdx.x * 256 + threadIdx.x;   // [0, 3*32768)
  const int a = i >> 15;
  const int j = i & 32767;
  const float* src = (a == 0) ? We : (a == 1) ? Wf : Wr;
  bf16*        dst = (a == 0) ? Web : (a == 1) ? Wfb : Wrb;
  dst[j] = (bf16)src[j];
}

// ---------------------------------------------------------------------------
// K0: transpose x (B,Cin,N) fp32 -> xt_hi/xt_lo (B,N,Cin) bf16 split, and
//     sq[b][n] = sum_c x^2 in fp32 (matches reference's fp32 sq).
// ---------------------------------------------------------------------------
__global__ __launch_bounds__(256) void k_prep(const float* __restrict__ x,
                                              bf16* __restrict__ xh,
                                              bf16* __restrict__ xl,
                                              float* __restrict__ sq) {
  __shared__ __attribute__((aligned(16))) bf16 th[64][136];
  __shared__ __attribute__((aligned(16))) bf16 tl[64][136];
  __shared__ float sqp[4][64];
  const int tid = threadIdx.x;
  const int b   = blockIdx.x >> 6;
  const int n0  = (blockIdx.x & 63) << 6;
  const int nl  = tid & 63;
  const int cg  = tid >> 6;
  const float* xb = x + (size_t)b * CIN * NPT;
  float acc = 0.f;
  #pragma unroll
  for (int rep = 0; rep < 32; ++rep) {
    const int c = rep * 4 + cg;
    const float v = xb[(size_t)c * NPT + n0 + nl];
    const bf16 h = (bf16)v;
    const bf16 l = (bf16)(v - (float)h);
    acc += v * v;
    th[nl][c] = h;
    tl[nl][c] = l;
  }
  sqp[cg][nl] = acc;
  __syncthreads();
  bf16* xho = xh + ((size_t)b * NPT + n0) * CIN;
  bf16* xlo = xl + ((size_t)b * NPT + n0) * CIN;
  #pragma unroll
  for (int rep = 0; rep < 32; ++rep) {
    const int e = rep * 256 + tid;
    const int r = e >> 7;
    const int c = e & 127;
    xho[(size_t)r * CIN + c] = th[r][c];
    xlo[(size_t)r * CIN + c] = tl[r][c];
  }
  if (tid < 64) {
    sq[b * NPT + n0 + tid] = sqp[0][tid] + sqp[1][tid] + sqp[2][tid] + sqp[3][tid];
  }
}

// ---------------------------------------------------------------------------
// K1: KNN, register-resident distances + branch-free bitonic selection.
// Block = 256 (4 waves) over 32 queries; wave w scans candidates
// [w*1024, (w+1)*1024). MFMA A=candidates, B=queries -> Gram in accumulators.
// Per lane-list, per 64-cand tile: 16 packed u64 keys (ord(d)<<32|idx) are
// bitonic-sorted then merged (lowest-16) into the running sorted list. Final:
// 16 sorted lists/query merged by a 4-level parallel tree in LDS. Key order =
// lexicographic (d, idx) -> exact lax.top_k tie semantics (ranges disjoint).
// Split-bf16 (hh+hl+lh) Gram: d2 err ~1e-4 << rank-16/17 gap.
// ---------------------------------------------------------------------------
__global__ __launch_bounds__(256, 2) void k_knn(const bf16* __restrict__ xh,
                                                const bf16* __restrict__ xl,
                                                const float* __restrict__ sq,
                                                int* __restrict__ knn_idx) {
  __shared__ u64 Lk[32][258];   // 32 queries x 16 runs x 16 keys (+pad)
  const int tid  = threadIdx.x;
  const int w    = tid >> 6;
  const int lane = tid & 63;
  const int col  = lane & 15;
  const int quad = lane >> 4;
  const int b    = blockIdx.x >> 7;          // 128 blocks per batch
  const int q0   = (blockIdx.x & 127) << 5;  // 32 queries per block
  const bf16*  xhb = xh + (size_t)b * NPT * CIN;
  const bf16*  xlb = xl + (size_t)b * NPT * CIN;
  const float* sqb = sq + b * NPT;

  // query fragments (B operand), 2 subtiles of 16 queries
  bf16x8 qh[2][4], ql[2][4];
  float sqn[2];
  #pragma unroll
  for (int t = 0; t < 2; ++t) {
    const bf16* qrh = xhb + (size_t)(q0 + t * 16 + col) * CIN + quad * 8;
    const bf16* qrl = xlb + (size_t)(q0 + t * 16 + col) * CIN + quad * 8;
    #pragma unroll
    for (int ks = 0; ks < 4; ++ks) {
      qh[t][ks] = *(const bf16x8*)(qrh + ks * 32);
      ql[t][ks] = *(const bf16x8*)(qrl + ks * 32);
    }
    sqn[t] = sqb[q0 + t * 16 + col];
  }

  u64 R0[16], R1[16];
  #pragma unroll
  for (int i = 0; i < 16; ++i) { R0[i] = ~0ull; R1[i] = ~0ull; }

  const int cbase = w << 10;
  for (int mt = 0; mt < 16; ++mt) {
    const int m0 = cbase + (mt << 6);
    u64 k0[16], k1[16];
    #pragma unroll
    for (int cb = 0; cb < 4; ++cb) {
      const bf16* crh = xhb + (size_t)(m0 + cb * 16 + col) * CIN + quad * 8;
      const bf16* crl = xlb + (size_t)(m0 + cb * 16 + col) * CIN + quad * 8;
      f32x4 a0 = {0.f, 0.f, 0.f, 0.f};
      f32x4 a1 = {0.f, 0.f, 0.f, 0.f};
      #pragma unroll
      for (int ks = 0; ks < 4; ++ks) {
        const bf16x8 ch_ = *(const bf16x8*)(crh + ks * 32);
        const bf16x8 cl_ = *(const bf16x8*)(crl + ks * 32);
        a0 = MFMA16x16(cl_, qh[0][ks], a0);
        a0 = MFMA16x16(ch_, ql[0][ks], a0);
        a0 = MFMA16x16(ch_, qh[0][ks], a0);
        a1 = MFMA16x16(cl_, qh[1][ks], a1);
        a1 = MFMA16x16(ch_, ql[1][ks], a1);
        a1 = MFMA16x16(ch_, qh[1][ks], a1);
      }
      const f32x4 sqm = *(const f32x4*)(sqb + m0 + cb * 16 + quad * 4);
      #pragma unroll
      for (int r = 0; r < 4; ++r) {
        const int m = m0 + cb * 16 + quad * 4 + r;
        k0[cb * 4 + r] = mk_key((sqn[0] + sqm[r]) - 2.0f * a0[r], m);
        k1[cb * 4 + r] = mk_key((sqn[1] + sqm[r]) - 2.0f * a1[r], m);
      }
    }
    sort16(k0); merge16(R0, k0);
    sort16(k1); merge16(R1, k1);
  }

  // dump: query q = t*16+col, run = w*4+quad (16 runs/query, disjoint cands)
  {
    const int run = (w << 2) | quad;
    const int qA = col;        // subtile 0
    const int qB = 16 | col;   // subtile 1
    #pragma unroll
    for (int i = 0; i < 16; ++i) {
      Lk[qA][run * 16 + i] = R0[i];
      Lk[qB][run * 16 + i] = R1[i];
    }
  }
  __syncthreads();

  // parallel tree merge: 16 -> 8 -> 4 -> 2 -> 1 runs per query
  #pragma unroll
  for (int half = 8; half >= 1; half >>= 1) {
    u64 A[16], Bv[16];
    const bool act = tid < 32 * half;
    const int q = tid / half;
    const int j = tid % half;
    if (act) {
      #pragma unroll
      for (int i = 0; i < 16; ++i) {
        A[i]  = Lk[q][(2 * j) * 16 + i];
        Bv[i] = Lk[q][(2 * j + 1) * 16 + i];
      }
    }
    __syncthreads();
    if (act) {
      merge16(A, Bv);
      #pragma unroll
      for (int i = 0; i < 16; ++i) Lk[q][j * 16 + i] = A[i];
    }
    __syncthreads();
  }

  if (tid < 32) {
    int* op = knn_idx + (size_t)(b * NPT + q0 + tid) * KNBR;
    #pragma unroll
    for (int i = 0; i < 16; ++i) op[i] = (int)(Lk[tid][i] & 0xFFFFFFFFull);
  }
}

// ---------------------------------------------------------------------------
// K2: edge MLP + attention + aggregate. One wave per point, 4 points per wave.
// Gathers hi+lo, reconstructs fp32, builds edge=[neigh-center, center] in LDS
// as bf16 (single rounding). h kept in fp32 registers; softmax + aggregate via
// shfl_xor reductions.
// ---------------------------------------------------------------------------
__global__ __launch_bounds__(256) void k_edge(const bf16* __restrict__ xh,
                                              const bf16* __restrict__ xl,
                                              const int* __restrict__ knn_idx,
                                              const bf16* __restrict__ We,
                                              const float* __restrict__ g1, const float* __restrict__ b1,
                                              const float* __restrict__ m1, const float* __restrict__ v1,
                                              const float* __restrict__ watt,
                                              bf16* __restrict__ agg) {
  __shared__ __attribute__((aligned(16))) bf16 Ew[4][16][264];
  __shared__ float s1[HED], t1[HED], wat[HED];
  const int tid  = threadIdx.x;
  const int w    = tid >> 6;
  const int lane = tid & 63;
  const int col  = lane & 15;
  const int quad = lane >> 4;
  if (tid < HED) {
    const float ss = g1[tid] / sqrtf(v1[tid] + 1e-5f);
    s1[tid] = ss;
    t1[tid] = b1[tid] - m1[tid] * ss;
    wat[tid] = watt[tid];
  }
  __syncthreads();
  const int gw = blockIdx.x * 4 + w;
  for (int it = 0; it < 4; ++it) {
    const int p = gw * 4 + it;
    const int b = p >> 12;
    const int n = p & 4095;
    const bf16* xhb = xh + (size_t)b * NPT * CIN;
    const bf16* xlb = xl + (size_t)b * NPT * CIN;
    const int my = knn_idx[(size_t)p * KNBR + col];
    const int m  = __shfl(my, lane >> 2);
    const int sub = lane & 3;
    const int kn  = lane >> 2;
    const bf16* nh = xhb + (size_t)m * CIN + sub * 32;
    const bf16* nl_ = xlb + (size_t)m * CIN + sub * 32;
    const bf16* ch = xhb + (size_t)n * CIN + sub * 32;
    const bf16* cl = xlb + (size_t)n * CIN + sub * 32;
    #pragma unroll
    for (int j = 0; j < 4; ++j) {
      const bf16x8 nhv = *(const bf16x8*)(nh + j * 8);
      const bf16x8 nlv = *(const bf16x8*)(nl_ + j * 8);
      const bf16x8 chv = *(const bf16x8*)(ch + j * 8);
      const bf16x8 clv = *(const bf16x8*)(cl + j * 8);
      bf16x8 dv, cv;
      #pragma unroll
      for (int e = 0; e < 8; ++e) {
        const float nf = (float)nhv[e] + (float)nlv[e];
        const float cf = (float)chv[e] + (float)clv[e];
        dv[e] = (bf16)(nf - cf);
        cv[e] = (bf16)cf;
      }
      *(bf16x8*)&Ew[w][kn][sub * 32 + j * 8]       = dv;
      *(bf16x8*)&Ew[w][kn][128 + sub * 32 + j * 8] = cv;
    }
    __syncthreads();
    const f32x4 zero4 = {0.f, 0.f, 0.f, 0.f};
    f32x4 acc[8];
    #pragma unroll
    for (int hb = 0; hb < 8; ++hb) acc[hb] = zero4;
    #pragma unroll
    for (int ks = 0; ks < 8; ++ks) {
      const bf16x8 af = *(const bf16x8*)&Ew[w][col][ks * 32 + quad * 8];
      #pragma unroll
      for (int hb = 0; hb < 8; ++hb) {
        const bf16x8 bfv = *(const bf16x8*)(We + (size_t)(hb * 16 + col) * 256 + ks * 32 + quad * 8);
        acc[hb] = MFMA16x16(af, bfv, acc[hb]);
      }
    }
    float h[8][4];
    float lg[4] = {0.f, 0.f, 0.f, 0.f};
    #pragma unroll
    for (int hb = 0; hb < 8; ++hb) {
      const int hc = hb * 16 + col;
      const float ss = s1[hc], tt = t1[hc], ww = wat[hc];
      #pragma unroll
      for (int r = 0; r < 4; ++r) {
        const float hv = fmaxf(acc[hb][r] * ss + tt, 0.f);
        h[hb][r] = hv;
        lg[r] += hv * ww;
      }
    }
    #pragma unroll
    for (int r = 0; r < 4; ++r) {
      float vv = lg[r];
      vv += __shfl_xor(vv, 1);
      vv += __shfl_xor(vv, 2);
      vv += __shfl_xor(vv, 4);
      vv += __shfl_xor(vv, 8);
      lg[r] = vv;
    }
    float mx = fmaxf(fmaxf(lg[0], lg[1]), fmaxf(lg[2], lg[3]));
    mx = fmaxf(mx, __shfl_xor(mx, 16));
    mx = fmaxf(mx, __shfl_xor(mx, 32));
    float ex[4];
    float sm = 0.f;
    #pragma unroll
    for (int r = 0; r < 4; ++r) { ex[r] = expf(lg[r] - mx); sm += ex[r]; }
    sm += __shfl_xor(sm, 16);
    sm += __shfl_xor(sm, 32);
    const float inv = 1.0f / sm;
    float ag[8];
    #pragma unroll
    for (int hb = 0; hb < 8; ++hb) {
      float a = h[hb][0] * ex[0] + h[hb][1] * ex[1] + h[hb][2] * ex[2] + h[hb][3] * ex[3];
      a += __shfl_xor(a, 16);
      a += __shfl_xor(a, 32);
      ag[hb] = a * inv;
    }
    if (quad == 0) {
      bf16* ao = agg + (size_t)p * HED;
      #pragma unroll
      for (int hb = 0; hb < 8; ++hb) ao[hb * 16 + col] = (bf16)ag[hb];
    }
    __syncthreads();
  }
}

// ---------------------------------------------------------------------------
// K3: fuse GEMM (B*N,128)x(128,256) + bn2 + relu -> outp bf16
// ---------------------------------------------------------------------------
__global__ __launch_bounds__(256) void k_fuse(const bf16* __restrict__ agg,
                                              const bf16* __restrict__ Wf,
                                              const float* __restrict__ g2, const float* __restrict__ b2,
                                              const float* __restrict__ m2, const float* __restrict__ v2,
                                              bf16* __restrict__ outp) {
  const int tid  = threadIdx.x;
  const int w    = tid >> 6;
  const int lane = tid & 63;
  const int col  = lane & 15;
  const int quad = lane >> 4;
  const int p0   = (blockIdx.x * 4 + w) * 16;
  bf16x8 afr[4];
  const bf16* arow = agg + (size_t)(p0 + col) * HED + quad * 8;
  #pragma unroll
  for (int ks = 0; ks < 4; ++ks) afr[ks] = *(const bf16x8*)(arow + ks * 32);
  #pragma unroll
  for (int ob = 0; ob < 16; ++ob) {
    f32x4 acc = {0.f, 0.f, 0.f, 0.f};
    const bf16* brow = Wf + (size_t)(ob * 16 + col) * HED + quad * 8;
    #pragma unroll
    for (int ks = 0; ks < 4; ++ks)
      acc = MFMA16x16(afr[ks], *(const bf16x8*)(brow + ks * 32), acc);
    const int o = ob * 16 + col;
    const float ss = g2[o] / sqrtf(v2[o] + 1e-5f);
    const float tt = b2[o] - m2[o] * ss;
    #pragma unroll
    for (int r = 0; r < 4; ++r) {
      outp[(size_t)(p0 + quad * 4 + r) * COUT + o] = (bf16)fmaxf(acc[r] * ss + tt, 0.f);
    }
  }
}

// ---------------------------------------------------------------------------
// K4: SE. One block per (b, chunk): mean over 256 pts -> fc1+relu -> fc2+sigmoid
// ---------------------------------------------------------------------------
__global__ __launch_bounds__(256) void k_se(const bf16* __restrict__ outp,
                                            const float* __restrict__ f1w, const float* __restrict__ f1b,
                                            const float* __restrict__ f2w, const float* __restrict__ f2b,
                                            float* __restrict__ sse) {
  __shared__ float mean_s[COUT];
  __shared__ float h1[64];
  const int bc  = blockIdx.x;   // b*16 + chunk
  const int tid = threadIdx.x;
  const bf16* base = outp + (size_t)bc * 256 * COUT;
  float s = 0.f;
  for (int p2 = 0; p2 < 256; ++p2) s += (float)base[(size_t)p2 * COUT + tid];
  mean_s[tid] = s * (1.0f / 256.0f);
  __syncthreads();
  if (tid < 64) {
    float a = f1b[tid];
    for (int c = 0; c < COUT; ++c) a += f1w[tid * COUT + c] * mean_s[c];
    h1[tid] = fmaxf(a, 0.f);
  }
  __syncthreads();
  float a = f2b[tid];
  #pragma unroll
  for (int j = 0; j < 64; ++j) a += f2w[tid * 64 + j] * h1[j];
  sse[(size_t)bc * COUT + tid] = 1.0f / (1.0f + expf(-a));
}

// ---------------------------------------------------------------------------
// K5: residual GEMM + bn3; out = outp*se + res, fp32, transposed (B,Cout,N)
// ---------------------------------------------------------------------------
__global__ __launch_bounds__(256) void k_final(const bf16* __restrict__ xh,
                                               const bf16* __restrict__ Wr,
                                               const float* __restrict__ g3, const float* __restrict__ b3,
                                               const float* __restrict__ m3, const float* __restrict__ v3,
                                               const bf16* __restrict__ outp,
                                               const float* __restrict__ sse,
                                               float* __restrict__ out) {
  const int tid  = threadIdx.x;
  const int w    = tid >> 6;
  const int lane = tid & 63;
  const int col  = lane & 15;
  const int quad = lane >> 4;
  const int p0   = (blockIdx.x * 4 + w) * 16;
  const int b    = p0 >> 12;
  const int n0l  = p0 & 4095;
  bf16x8 afr[4];
  const bf16* arow = xh + (size_t)(p0 + col) * CIN + quad * 8;
  #pragma unroll
  for (int ks = 0; ks < 4; ++ks) afr[ks] = *(const bf16x8*)(arow + ks * 32);
  const float* scb = sse + (size_t)(b * 16 + (n0l >> 8)) * COUT;
  #pragma unroll
  for (int ob = 0; ob < 16; ++ob) {
    f32x4 acc = {0.f, 0.f, 0.f, 0.f};
    const bf16* brow = Wr + (size_t)(ob * 16 + col) * CIN + quad * 8;
    #pragma unroll
    for (int ks = 0; ks < 4; ++ks)
      acc = MFMA16x16(afr[ks], *(const bf16x8*)(brow + ks * 32), acc);
    const int o = ob * 16 + col;
    const float ss = g3[o] / sqrtf(v3[o] + 1e-5f);
    const float tt = b3[o] - m3[o] * ss;
    const float sc = scb[o];
    f32x4 pk;
    #pragma unroll
    for (int r = 0; r < 4; ++r) {
      const float res = acc[r] * ss + tt;
      pk[r] = (float)outp[(size_t)(p0 + quad * 4 + r) * COUT + o] * sc + res;
    }
    float* op = out + (size_t)(b * COUT + o) * NPT + n0l + quad * 4;
    *(f32x4*)op = pk;
  }
}

// ---------------------------------------------------------------------------
extern "C" void kernel_launch(void* const* d_in, const int* in_sizes, int n_in,
                              void* d_out, int out_size, void* d_ws, size_t ws_size,
                              hipStream_t stream) {
  (void)in_sizes; (void)n_in; (void)out_size; (void)ws_size;
  const float* x    = (const float*)d_in[0];
  const float* We   = (const float*)d_in[1];
  const float* g1   = (const float*)d_in[2];
  const float* b1   = (const float*)d_in[3];
  const float* m1   = (const float*)d_in[4];
  const float* v1   = (const float*)d_in[5];
  const float* watt = (const float*)d_in[6];
  const float* Wf   = (const float*)d_in[7];
  const float* g2   = (const float*)d_in[8];
  const float* b2   = (const float*)d_in[9];
  const float* m2   = (const float*)d_in[10];
  const float* v2   = (const float*)d_in[11];
  const float* f1w  = (const float*)d_in[12];
  const float* f1b  = (const float*)d_in[13];
  const float* f2w  = (const float*)d_in[14];
  const float* f2b  = (const float*)d_in[15];
  const float* Wr   = (const float*)d_in[16];
  const float* g3   = (const float*)d_in[17];
  const float* b3   = (const float*)d_in[18];
  const float* m3   = (const float*)d_in[19];
  const float* v3   = (const float*)d_in[20];

  char* ws = (char*)d_ws;
  size_t off = 0;
  bf16*  xth  = (bf16*)(ws + off);  off += (size_t)BB * NPT * CIN * 2;        // 4 MB
  bf16*  xtl  = (bf16*)(ws + off);  off += (size_t)BB * NPT * CIN * 2;        // 4 MB
  float* sq   = (float*)(ws + off); off += (size_t)BB * NPT * 4;              // 64 KB
  int*   idxp = (int*)(ws + off);   off += (size_t)BB * NPT * KNBR * 4;       // 1 MB
  bf16*  aggp = (bf16*)(ws + off);  off += (size_t)BB * NPT * HED * 2;        // 4 MB
  bf16*  outp = (bf16*)(ws + off);  off += (size_t)BB * NPT * COUT * 2;       // 8 MB
  float* ssep = (float*)(ws + off); off += (size_t)BB * 16 * COUT * 4;        // 64 KB
  bf16*  Web  = (bf16*)(ws + off);  off += (size_t)HED * 2 * CIN * 2;         // 64 KB
  bf16*  Wfb  = (bf16*)(ws + off);  off += (size_t)COUT * HED * 2;            // 64 KB
  bf16*  Wrb  = (bf16*)(ws + off);  off += (size_t)COUT * CIN * 2;            // 64 KB

  float* out = (float*)d_out;

  k_wconv<<<384, 256, 0, stream>>>(We, Wf, Wr, Web, Wfb, Wrb);
  k_prep<<<256, 256, 0, stream>>>(x, xth, xtl, sq);
  k_knn<<<512, 256, 0, stream>>>(xth, xtl, sq, idxp);
  k_edge<<<1024, 256, 0, stream>>>(xth, xtl, idxp, Web, g1, b1, m1, v1, watt, aggp);
  k_fuse<<<256, 256, 0, stream>>>(aggp, Wfb, g2, b2, m2, v2, outp);
  k_se<<<64, 256, 0, stream>>>(outp, f1w, f1b, f2w, f2b, ssep);
  k_final<<<256, 256, 0, stream>>>(xth, Wrb, g3, b3, m3, v3, outp, ssep, out);
}